// Round 12
// baseline (97.466 us; speedup 1.0000x reference)
//
#include <hip/hip_runtime.h>
#include <hip/hip_bf16.h>

#define T_STEPS 100
#define D_IN    65536
#define HID     256
#define HTOT    512
#define BETA    0.95f
#define THRESH  1.0f

typedef __bf16 bf16x8 __attribute__((ext_vector_type(8)));
typedef float  f32x16 __attribute__((ext_vector_type(16)));

__device__ __forceinline__ void gload_lds16(const void* g, void* l) {
    __builtin_amdgcn_global_load_lds(
        (const __attribute__((address_space(1))) void*)g,
        (__attribute__((address_space(3))) void*)l, 16, 0, 0);
}

// ---- x pre-pack: fp32 -> bf16 hi/mid blobs, one 16-KB blob per 32-k block.
// Blob layout == gemm1 LDS x-layout: granule G(r,slot) = r*4 + (slot^((r>>1)&3)),
// hi at G*16 bytes, mid at 8 KB + G*16. Rows 100..127 zero-padded.
__global__ __launch_bounds__(512) void k_xpack(
    const float* __restrict__ x, __bf16* __restrict__ xp)
{
    const int idx  = blockIdx.x * 512 + threadIdx.x;
    const int slot = idx & 3;
    const int r    = (idx >> 2) & 127;
    const int gk   = idx >> 9;

    float f[8] = {0.f, 0.f, 0.f, 0.f, 0.f, 0.f, 0.f, 0.f};
    if (r < T_STEPS) {
        const float* src = x + (size_t)r * D_IN + gk * 32 + slot * 8;
        float4 v0 = *(const float4*)src;
        float4 v1 = *(const float4*)(src + 4);
        f[0] = v0.x; f[1] = v0.y; f[2] = v0.z; f[3] = v0.w;
        f[4] = v1.x; f[5] = v1.y; f[6] = v1.z; f[7] = v1.w;
    }
    bf16x8 hi, mi;
#pragma unroll
    for (int e = 0; e < 8; e++) {
        __bf16 h = (__bf16)f[e];
        hi[e] = h; mi[e] = (__bf16)(f[e] - (float)h);
    }
    const int G = r * 4 + (slot ^ ((r >> 1) & 3));
    __bf16* blob = xp + (size_t)gk * 8192;
    *(bf16x8*)(blob + G * 8)        = hi;
    *(bf16x8*)(blob + 4096 + G * 8) = mi;
}

// ---- GEMM1 (R11 staging/swizzle + quadrant waves).
// 2-buffer gload_lds pipeline, 64 KB LDS -> 2 blocks/CU. Per 32-k step-buffer
// (32 KB): [0,8K) x_h, [8K,16K) x_m, [16K,32K) W fp32 (row-swizzled source).
// Block = 256 thr = 4 waves, each wave owns a 64t x 64h QUADRANT (2x2 accs):
// -33% LDS reads/step, narrower barriers, 4 MFMA chains/wave.
// XCD-locality flat-grid swizzle identical to R11.
__global__ __launch_bounds__(256, 2) void k_gemm1(
    const float* __restrict__ aW1,   // [256][65536]
    const float* __restrict__ cW1,   // [256][65536]
    const __bf16* __restrict__ xp,   // packed x blobs
    float* __restrict__ P,           // [NS][100][512]
    int nsteps)                      // 32-k steps per split (16 at NS=128)
{
    // bijective swizzle: d in [0,512) -> xcd = d%8, slot = d/8 (0..63),
    // s = xcd*16 + (slot & 15)  (0..127), ht = slot >> 4 (0..3)
    const int d    = blockIdx.x;
    const int xcd  = d & 7;
    const int sl   = d >> 3;
    const int s    = xcd * 16 + (sl & 15);
    const int ht   = sl >> 4;

    const int tid  = threadIdx.x;
    const int lane = tid & 63;
    const int l31  = lane & 31;
    const int h5   = lane >> 5;
    const int wv   = tid >> 6;           // 0..3
    const int wt   = (wv & 1) * 64;      // wave t-offset
    const int wh   = (wv >> 1) * 64;     // wave h-offset (64-wide quadrant)

    __shared__ __align__(16) char smem[2][32768];   // 64 KB

    const float* Wbase = (ht < 2) ? (aW1 + (size_t)ht * 128 * D_IN)
                                  : (cW1 + (size_t)(ht - 2) * 128 * D_IN);

    // staging: 8 gload_lds per thread per step (1024 x-granules + 1024 W-granules)
    const float* wsrc[4];
#pragma unroll
    for (int o = 0; o < 4; o++) {
        const int idx = o * 256 + tid;
        const int row = idx >> 3, wj = idx & 7;
        wsrc[o] = Wbase + (size_t)row * D_IN + (wj ^ (row & 7)) * 4;
    }
    const int gk0 = s * nsteps;

    f32x16 acc00, acc01, acc10, acc11;
#pragma unroll
    for (int i = 0; i < 16; i++) {
        acc00[i] = 0.f; acc01[i] = 0.f; acc10[i] = 0.f; acc11[i] = 0.f;
    }

#define STAGE(i) do {                                                         \
    char* b_ = smem[(i) & 1];                                                 \
    const __bf16* xb_ = xp + (size_t)(gk0 + (i)) * 8192;                      \
    const int kc_ = (gk0 + (i)) * 32;                                         \
    _Pragma("unroll")                                                         \
    for (int o = 0; o < 4; o++) {                                             \
        const int g_ = o * 256 + tid;                                         \
        gload_lds16(xb_ + g_ * 8, b_ + g_ * 16);                              \
    }                                                                         \
    _Pragma("unroll")                                                         \
    for (int o = 0; o < 4; o++) {                                             \
        const int g_ = o * 256 + tid;                                         \
        gload_lds16(wsrc[o] + kc_, b_ + 16384 + g_ * 16);                     \
    }                                                                         \
} while (0)

#define CVT8(dsth, dstm, va, vb) do {                                         \
    float f_[8] = {va.x, va.y, va.z, va.w, vb.x, vb.y, vb.z, vb.w};           \
    _Pragma("unroll")                                                         \
    for (int e = 0; e < 8; e++) {                                             \
        __bf16 h = (__bf16)f_[e];                                             \
        dsth[e] = h; dstm[e] = (__bf16)(f_[e] - (float)h);                    \
    }                                                                         \
} while (0)

#define COMPUTE(i) do {                                                       \
    const char* b_ = smem[(i) & 1];                                           \
    _Pragma("unroll")                                                         \
    for (int s16 = 0; s16 < 2; s16++) {                                       \
        /* A fragments (t quadrant rows) */                                   \
        const int slot_ = s16 * 2 + h5;                                       \
        const int r0 = wt + l31, r1 = r0 + 32;                                \
        const int G0 = r0 * 4 + (slot_ ^ ((r0 >> 1) & 3));                    \
        const int G1 = r1 * 4 + (slot_ ^ ((r1 >> 1) & 3));                    \
        bf16x8 a0h = *(const bf16x8*)(b_ + G0 * 16);                          \
        bf16x8 a0m = *(const bf16x8*)(b_ + 8192 + G0 * 16);                   \
        bf16x8 a1h = *(const bf16x8*)(b_ + G1 * 16);                          \
        bf16x8 a1m = *(const bf16x8*)(b_ + 8192 + G1 * 16);                   \
        /* W fragments: two 32-row h-sets of the 64h quadrant */              \
        const int gb = s16 * 4 + h5 * 2;                                      \
        const int hrA = wh + l31, hrB = hrA + 32;                             \
        const char* wrA_ = b_ + 16384 + hrA * 128;                            \
        const char* wrB_ = b_ + 16384 + hrB * 128;                            \
        float4 waA = *(const float4*)(wrA_ + ((gb ^ (hrA & 7)) * 16));        \
        float4 wbA = *(const float4*)(wrA_ + (((gb + 1) ^ (hrA & 7)) * 16));  \
        float4 waB = *(const float4*)(wrB_ + ((gb ^ (hrB & 7)) * 16));        \
        float4 wbB = *(const float4*)(wrB_ + (((gb + 1) ^ (hrB & 7)) * 16));  \
        bf16x8 bhA, bmA, bhB, bmB;                                            \
        CVT8(bhA, bmA, waA, wbA);                                             \
        CVT8(bhB, bmB, waB, wbB);                                             \
        acc00 = __builtin_amdgcn_mfma_f32_32x32x16_bf16(a0m, bhA, acc00, 0,0,0); \
        acc00 = __builtin_amdgcn_mfma_f32_32x32x16_bf16(a0h, bmA, acc00, 0,0,0); \
        acc00 = __builtin_amdgcn_mfma_f32_32x32x16_bf16(a0h, bhA, acc00, 0,0,0); \
        acc01 = __builtin_amdgcn_mfma_f32_32x32x16_bf16(a0m, bhB, acc01, 0,0,0); \
        acc01 = __builtin_amdgcn_mfma_f32_32x32x16_bf16(a0h, bmB, acc01, 0,0,0); \
        acc01 = __builtin_amdgcn_mfma_f32_32x32x16_bf16(a0h, bhB, acc01, 0,0,0); \
        acc10 = __builtin_amdgcn_mfma_f32_32x32x16_bf16(a1m, bhA, acc10, 0,0,0); \
        acc10 = __builtin_amdgcn_mfma_f32_32x32x16_bf16(a1h, bmA, acc10, 0,0,0); \
        acc10 = __builtin_amdgcn_mfma_f32_32x32x16_bf16(a1h, bhA, acc10, 0,0,0); \
        acc11 = __builtin_amdgcn_mfma_f32_32x32x16_bf16(a1m, bhB, acc11, 0,0,0); \
        acc11 = __builtin_amdgcn_mfma_f32_32x32x16_bf16(a1h, bmB, acc11, 0,0,0); \
        acc11 = __builtin_amdgcn_mfma_f32_32x32x16_bf16(a1h, bhB, acc11, 0,0,0); \
    }                                                                         \
} while (0)

    STAGE(0);
    STAGE(1);
    for (int i = 0; i < nsteps; i++) {
        if (i + 1 < nsteps) asm volatile("s_waitcnt vmcnt(8)" ::: "memory");
        else                asm volatile("s_waitcnt vmcnt(0)" ::: "memory");
        __builtin_amdgcn_s_barrier();              // buf[i&1] staged for all
        __builtin_amdgcn_sched_barrier(0);
        COMPUTE(i);
        __builtin_amdgcn_s_barrier();              // all waves done with buf
        __builtin_amdgcn_sched_barrier(0);
        if (i + 2 < nsteps) STAGE(i + 2);          // rides the next step
    }
#undef STAGE
#undef CVT8
#undef COMPUTE

    // ---- store partials
    const int rbase = 4 * h5;
    float* Pb = P + (size_t)s * T_STEPS * HTOT;
    const int hA = ht * 128 + wh + l31;
    const int hB = hA + 32;
#pragma unroll
    for (int reg = 0; reg < 16; reg++) {
        const int row = (reg & 3) + rbase + 8 * (reg >> 2);
        const int t0  = wt + row;
        const int t1  = wt + 32 + row;
        if (t0 < T_STEPS) {
            Pb[(size_t)t0 * HTOT + hA] = acc00[reg];
            Pb[(size_t)t0 * HTOT + hB] = acc01[reg];
        }
        if (t1 < T_STEPS) {
            Pb[(size_t)t1 * HTOT + hA] = acc10[reg];
            Pb[(size_t)t1 * HTOT + hB] = acc11[reg];
        }
    }
}

// reduce partials + bias -> cur1[t][h]   (float4 per thread, coalesced)
__global__ __launch_bounds__(256) void k_reduce(
    const float* __restrict__ P,
    const float* __restrict__ ab1, const float* __restrict__ cb1,
    float* __restrict__ cur1, int NS)
{
    int g4 = blockIdx.x * 256 + threadIdx.x;
    int g  = g4 * 4;
    int h0 = g & (HTOT - 1);
    float4 sum;
    sum.x = (h0 + 0 < HID) ? ab1[h0 + 0] : cb1[h0 + 0 - HID];
    sum.y = (h0 + 1 < HID) ? ab1[h0 + 1] : cb1[h0 + 1 - HID];
    sum.z = (h0 + 2 < HID) ? ab1[h0 + 2] : cb1[h0 + 2 - HID];
    sum.w = (h0 + 3 < HID) ? ab1[h0 + 3] : cb1[h0 + 3 - HID];
    for (int ss = 0; ss < NS; ss++) {
        float4 v = *(const float4*)(P + (size_t)ss * T_STEPS * HTOT + g);
        sum.x += v.x; sum.y += v.y; sum.z += v.z; sum.w += v.w;
    }
    *(float4*)(cur1 + g) = sum;
}

// LIF1: 8 blocks x 64 threads, thread = neuron, 10-deep current prefetch.
__global__ __launch_bounds__(64) void k_lif1(
    const float* __restrict__ cur1,
    unsigned long long* __restrict__ bitsws,
    float* __restrict__ wsa)
{
    const int b    = blockIdx.x;
    const int lane = threadIdx.x;
    const int n    = b * 64 + lane;

    float mem = 0.f;
    for (int tb = 0; tb < T_STEPS; tb += 10) {
        float c[10];
#pragma unroll
        for (int i = 0; i < 10; i++) c[i] = cur1[(size_t)(tb + i) * HTOT + n];
#pragma unroll
        for (int i = 0; i < 10; i++) {
            float reset = (mem > THRESH) ? THRESH : 0.f;
            mem = BETA * mem + c[i] - reset;
            unsigned long long m = __ballot(mem > THRESH);
            if (lane == 0) bitsws[(size_t)(tb + i) * 8 + b] = m;
        }
    }
    if (b == 0 && lane == 0) { wsa[0] = 0.f; wsa[1] = 0.f; }
}

// GEMM2 + LIF2: block per output neuron j (0..19 actor, 20 critic).
__global__ __launch_bounds__(128) void k_gemm2(
    const unsigned long long* __restrict__ bitsws,
    const float* __restrict__ aW2, const float* __restrict__ ab2,
    const float* __restrict__ cW2, const float* __restrict__ cb2,
    float* __restrict__ wsa, float* __restrict__ out)
{
    const int j   = blockIdx.x;
    const int tid = threadIdx.x;

    __shared__ float W[256];
    __shared__ float c2[T_STEPS];

    const float* Wsrc = (j < 20) ? (aW2 + j * 256) : cW2;
    for (int i = tid; i < 256; i += 128) W[i] = Wsrc[i];
    const float bias  = (j < 20) ? ab2[j] : cb2[0];
    const int   wbase = (j < 20) ? 0 : 4;
    __syncthreads();

    const int t = tid;
    if (t < T_STEPS) {
        unsigned long long m0 = bitsws[(size_t)t * 8 + wbase + 0];
        unsigned long long m1 = bitsws[(size_t)t * 8 + wbase + 1];
        unsigned long long m2 = bitsws[(size_t)t * 8 + wbase + 2];
        unsigned long long m3 = bitsws[(size_t)t * 8 + wbase + 3];
        float acc = bias;
#pragma unroll
        for (int bitp = 0; bitp < 64; bitp++) {
            acc += ((m0 >> bitp) & 1ULL) ? W[bitp]       : 0.f;
            acc += ((m1 >> bitp) & 1ULL) ? W[64 + bitp]  : 0.f;
            acc += ((m2 >> bitp) & 1ULL) ? W[128 + bitp] : 0.f;
            acc += ((m3 >> bitp) & 1ULL) ? W[192 + bitp] : 0.f;
        }
        c2[t] = acc;
    }
    __syncthreads();

    if (tid == 0) {
        float mem = 0.f, spk = 0.f;
        for (int tt = 0; tt < T_STEPS; tt++) {
            float reset = (mem > THRESH) ? THRESH : 0.f;
            mem = BETA * mem + c2[tt] - reset;
            spk += (mem > THRESH) ? 1.f : 0.f;
        }
        if (j < 10)       atomicAdd(&wsa[0], spk);   // exact: integer-valued floats
        else if (j < 20)  atomicAdd(&wsa[1], spk);
        else              out[2] = mem;
    }
}

__global__ __launch_bounds__(64) void k_final(
    const float* __restrict__ wsa, float* __restrict__ out)
{
    if (threadIdx.x == 0) {
        float a0 = wsa[0], a1 = wsa[1];
        float mx = fmaxf(a0, a1);
        float e0 = expf(a0 - mx), e1 = expf(a1 - mx);
        float inv = 1.f / (e0 + e1);
        out[0] = e0 * inv;
        out[1] = e1 * inv;
    }
}

extern "C" void kernel_launch(void* const* d_in, const int* in_sizes, int n_in,
                              void* d_out, int out_size, void* d_ws, size_t ws_size,
                              hipStream_t stream) {
    const float* x   = (const float*)d_in[0];
    const float* aW1 = (const float*)d_in[1];
    const float* ab1 = (const float*)d_in[2];
    const float* aW2 = (const float*)d_in[3];
    const float* ab2 = (const float*)d_in[4];
    const float* cW1 = (const float*)d_in[5];
    const float* cb1 = (const float*)d_in[6];
    const float* cW2 = (const float*)d_in[7];
    const float* cb2 = (const float*)d_in[8];
    float* out = (float*)d_out;

    const size_t xpack_bytes = 2048ull * 16384;            // 33.55 MB
    const int NS = 128;                                    // fixed (swizzle assumes 128)
    const int nsteps = (D_IN / NS) / 32;                   // 16

    __bf16* xpack = (__bf16*)d_ws;
    float*  P     = (float*)((char*)d_ws + xpack_bytes);   // [128][100][512]
    float*  cur1  = P + (size_t)NS * T_STEPS * HTOT;       // [100][512]
    unsigned long long* bitsws =
        (unsigned long long*)(cur1 + T_STEPS * HTOT);      // [100][8]
    float* wsa = (float*)(bitsws + T_STEPS * 8);           // [2]

    k_xpack <<<2048, 512, 0, stream>>>(x, xpack);
    k_gemm1 <<<512, 256, 0, stream>>>(aW1, cW1, xpack, P, nsteps);
    k_reduce<<<(T_STEPS * HTOT / 4) / 256, 256, 0, stream>>>(P, ab1, cb1, cur1, NS);
    k_lif1  <<<8, 64, 0, stream>>>(cur1, bitsws, wsa);
    k_gemm2 <<<21, 128, 0, stream>>>(bitsws, aW2, ab2, cW2, cb2, wsa, out);
    k_final <<<1, 64, 0, stream>>>(wsa, out);
}

// Round 13
// 92.773 us; speedup vs baseline: 1.0506x; 1.0506x over previous
//
#include <hip/hip_runtime.h>
#include <hip/hip_bf16.h>

#define T_STEPS 100
#define D_IN    65536
#define HID     256
#define HTOT    512
#define BETA    0.95f
#define THRESH  1.0f

typedef __bf16 bf16x8 __attribute__((ext_vector_type(8)));
typedef float  f32x16 __attribute__((ext_vector_type(16)));

__device__ __forceinline__ void gload_lds16(const void* g, void* l) {
    __builtin_amdgcn_global_load_lds(
        (const __attribute__((address_space(1))) void*)g,
        (__attribute__((address_space(3))) void*)l, 16, 0, 0);
}

// ---- GEMM1 (R12 structure, xpack folded in: x staged fp32 + converted
// in-COMPUTE like W). 2-buffer gload_lds pipeline, 64 KB LDS -> 2 blocks/CU.
// Per 32-k step-buffer (32 KB): [0,16K) x fp32 [128 rows][8 swz granules],
// [16K,32K) W fp32 (same layout). Row r of A only affects C row t=r, and
// t>=100 is never stored -> pad rows may hold garbage (source row clamped to
// 99 to stay in-bounds). 3-product bf16 hi/mid MFMA, order identical to R12.
// Block = 256 thr = 4 waves, each wave owns a 64t x 64h quadrant (2x2 accs).
// XCD-locality flat-grid swizzle identical to R11/R12.
__global__ __launch_bounds__(256, 2) void k_gemm1(
    const float* __restrict__ aW1,   // [256][65536]
    const float* __restrict__ cW1,   // [256][65536]
    const float* __restrict__ x,     // [100][65536]
    float* __restrict__ P,           // [NS][100][512]
    int nsteps)                      // 32-k steps per split (16 at NS=128)
{
    // bijective swizzle: d in [0,512) -> xcd = d%8, slot = d/8 (0..63),
    // s = xcd*16 + (slot & 15)  (0..127), ht = slot >> 4 (0..3)
    const int d    = blockIdx.x;
    const int xcd  = d & 7;
    const int sl   = d >> 3;
    const int s    = xcd * 16 + (sl & 15);
    const int ht   = sl >> 4;

    const int tid  = threadIdx.x;
    const int lane = tid & 63;
    const int l31  = lane & 31;
    const int h5   = lane >> 5;
    const int wv   = tid >> 6;           // 0..3
    const int wt   = (wv & 1) * 64;      // wave t-offset
    const int wh   = (wv >> 1) * 64;     // wave h-offset (64-wide quadrant)

    __shared__ __align__(16) char smem[2][32768];   // 64 KB

    const float* Wbase = (ht < 2) ? (aW1 + (size_t)ht * 128 * D_IN)
                                  : (cW1 + (size_t)(ht - 2) * 128 * D_IN);

    // staging: 8 gload_lds per thread per step (1024 x + 1024 W granules).
    // granule idx = o*256+tid -> (row = idx>>3, g = idx&7); LDS dest linear,
    // source column pre-swizzled (g ^ (row&7)) so swizzled LDS reads pair up.
    const float* xsrc[4];
    const float* wsrc[4];
#pragma unroll
    for (int o = 0; o < 4; o++) {
        const int idx = o * 256 + tid;
        const int row = idx >> 3, g = idx & 7;
        const int xrow = (row < T_STEPS) ? row : (T_STEPS - 1);  // clamp: pad rows = garbage, discarded at store
        xsrc[o] = x     + (size_t)xrow * D_IN + (g ^ (row & 7)) * 4;
        wsrc[o] = Wbase + (size_t)row  * D_IN + (g ^ (row & 7)) * 4;
    }
    const int gk0 = s * nsteps;

    f32x16 acc00, acc01, acc10, acc11;
#pragma unroll
    for (int i = 0; i < 16; i++) {
        acc00[i] = 0.f; acc01[i] = 0.f; acc10[i] = 0.f; acc11[i] = 0.f;
    }

#define STAGE(i) do {                                                         \
    char* b_ = smem[(i) & 1];                                                 \
    const int kc_ = (gk0 + (i)) * 32;                                         \
    _Pragma("unroll")                                                         \
    for (int o = 0; o < 4; o++) {                                             \
        const int g_ = o * 256 + tid;                                         \
        gload_lds16(xsrc[o] + kc_, b_ + g_ * 16);                             \
    }                                                                         \
    _Pragma("unroll")                                                         \
    for (int o = 0; o < 4; o++) {                                             \
        const int g_ = o * 256 + tid;                                         \
        gload_lds16(wsrc[o] + kc_, b_ + 16384 + g_ * 16);                     \
    }                                                                         \
} while (0)

#define CVT8(dsth, dstm, va, vb) do {                                         \
    float f_[8] = {va.x, va.y, va.z, va.w, vb.x, vb.y, vb.z, vb.w};           \
    _Pragma("unroll")                                                         \
    for (int e = 0; e < 8; e++) {                                             \
        __bf16 h = (__bf16)f_[e];                                             \
        dsth[e] = h; dstm[e] = (__bf16)(f_[e] - (float)h);                    \
    }                                                                         \
} while (0)

#define COMPUTE(i) do {                                                       \
    const char* b_ = smem[(i) & 1];                                           \
    _Pragma("unroll")                                                         \
    for (int s16 = 0; s16 < 2; s16++) {                                       \
        const int slot_ = s16 * 2 + h5;                                       \
        const int gb    = slot_ * 2;                                          \
        /* A fragments: x fp32 rows r0, r1, granules gb/gb+1 (swizzled) */    \
        const int r0 = wt + l31, r1 = r0 + 32;                                \
        const char* xr0_ = b_ + r0 * 128;                                     \
        const char* xr1_ = b_ + r1 * 128;                                     \
        float4 xa0 = *(const float4*)(xr0_ + ((gb ^ (r0 & 7)) * 16));         \
        float4 xb0 = *(const float4*)(xr0_ + (((gb + 1) ^ (r0 & 7)) * 16));   \
        float4 xa1 = *(const float4*)(xr1_ + ((gb ^ (r1 & 7)) * 16));         \
        float4 xb1 = *(const float4*)(xr1_ + (((gb + 1) ^ (r1 & 7)) * 16));   \
        bf16x8 a0h, a0m, a1h, a1m;                                            \
        CVT8(a0h, a0m, xa0, xb0);                                             \
        CVT8(a1h, a1m, xa1, xb1);                                             \
        /* W fragments: two 32-row h-sets of the 64h quadrant */              \
        const int hrA = wh + l31, hrB = hrA + 32;                             \
        const char* wrA_ = b_ + 16384 + hrA * 128;                            \
        const char* wrB_ = b_ + 16384 + hrB * 128;                            \
        float4 waA = *(const float4*)(wrA_ + ((gb ^ (hrA & 7)) * 16));        \
        float4 wbA = *(const float4*)(wrA_ + (((gb + 1) ^ (hrA & 7)) * 16));  \
        float4 waB = *(const float4*)(wrB_ + ((gb ^ (hrB & 7)) * 16));        \
        float4 wbB = *(const float4*)(wrB_ + (((gb + 1) ^ (hrB & 7)) * 16));  \
        bf16x8 bhA, bmA, bhB, bmB;                                            \
        CVT8(bhA, bmA, waA, wbA);                                             \
        CVT8(bhB, bmB, waB, wbB);                                             \
        acc00 = __builtin_amdgcn_mfma_f32_32x32x16_bf16(a0m, bhA, acc00, 0,0,0); \
        acc00 = __builtin_amdgcn_mfma_f32_32x32x16_bf16(a0h, bmA, acc00, 0,0,0); \
        acc00 = __builtin_amdgcn_mfma_f32_32x32x16_bf16(a0h, bhA, acc00, 0,0,0); \
        acc01 = __builtin_amdgcn_mfma_f32_32x32x16_bf16(a0m, bhB, acc01, 0,0,0); \
        acc01 = __builtin_amdgcn_mfma_f32_32x32x16_bf16(a0h, bmB, acc01, 0,0,0); \
        acc01 = __builtin_amdgcn_mfma_f32_32x32x16_bf16(a0h, bhB, acc01, 0,0,0); \
        acc10 = __builtin_amdgcn_mfma_f32_32x32x16_bf16(a1m, bhA, acc10, 0,0,0); \
        acc10 = __builtin_amdgcn_mfma_f32_32x32x16_bf16(a1h, bmA, acc10, 0,0,0); \
        acc10 = __builtin_amdgcn_mfma_f32_32x32x16_bf16(a1h, bhA, acc10, 0,0,0); \
        acc11 = __builtin_amdgcn_mfma_f32_32x32x16_bf16(a1m, bhB, acc11, 0,0,0); \
        acc11 = __builtin_amdgcn_mfma_f32_32x32x16_bf16(a1h, bmB, acc11, 0,0,0); \
        acc11 = __builtin_amdgcn_mfma_f32_32x32x16_bf16(a1h, bhB, acc11, 0,0,0); \
    }                                                                         \
} while (0)

    STAGE(0);
    STAGE(1);
    for (int i = 0; i < nsteps; i++) {
        if (i + 1 < nsteps) asm volatile("s_waitcnt vmcnt(8)" ::: "memory");
        else                asm volatile("s_waitcnt vmcnt(0)" ::: "memory");
        __builtin_amdgcn_s_barrier();              // buf[i&1] staged for all
        __builtin_amdgcn_sched_barrier(0);
        COMPUTE(i);
        __builtin_amdgcn_s_barrier();              // all waves done with buf
        __builtin_amdgcn_sched_barrier(0);
        if (i + 2 < nsteps) STAGE(i + 2);          // rides the next step
    }
#undef STAGE
#undef CVT8
#undef COMPUTE

    // ---- store partials (t >= 100 discarded -> pad-row garbage never escapes)
    const int rbase = 4 * h5;
    float* Pb = P + (size_t)s * T_STEPS * HTOT;
    const int hA = ht * 128 + wh + l31;
    const int hB = hA + 32;
#pragma unroll
    for (int reg = 0; reg < 16; reg++) {
        const int row = (reg & 3) + rbase + 8 * (reg >> 2);
        const int t0  = wt + row;
        const int t1  = wt + 32 + row;
        if (t0 < T_STEPS) {
            Pb[(size_t)t0 * HTOT + hA] = acc00[reg];
            Pb[(size_t)t0 * HTOT + hB] = acc01[reg];
        }
        if (t1 < T_STEPS) {
            Pb[(size_t)t1 * HTOT + hA] = acc10[reg];
            Pb[(size_t)t1 * HTOT + hB] = acc11[reg];
        }
    }
}

// reduce partials + bias -> cur1[t][h]   (float4 per thread, coalesced)
__global__ __launch_bounds__(256) void k_reduce(
    const float* __restrict__ P,
    const float* __restrict__ ab1, const float* __restrict__ cb1,
    float* __restrict__ cur1, int NS)
{
    int g4 = blockIdx.x * 256 + threadIdx.x;
    int g  = g4 * 4;
    int h0 = g & (HTOT - 1);
    float4 sum;
    sum.x = (h0 + 0 < HID) ? ab1[h0 + 0] : cb1[h0 + 0 - HID];
    sum.y = (h0 + 1 < HID) ? ab1[h0 + 1] : cb1[h0 + 1 - HID];
    sum.z = (h0 + 2 < HID) ? ab1[h0 + 2] : cb1[h0 + 2 - HID];
    sum.w = (h0 + 3 < HID) ? ab1[h0 + 3] : cb1[h0 + 3 - HID];
    for (int ss = 0; ss < NS; ss++) {
        float4 v = *(const float4*)(P + (size_t)ss * T_STEPS * HTOT + g);
        sum.x += v.x; sum.y += v.y; sum.z += v.z; sum.w += v.w;
    }
    *(float4*)(cur1 + g) = sum;
}

// LIF1: 8 blocks x 64 threads, thread = neuron, 10-deep current prefetch.
__global__ __launch_bounds__(64) void k_lif1(
    const float* __restrict__ cur1,
    unsigned long long* __restrict__ bitsws,
    float* __restrict__ wsa)
{
    const int b    = blockIdx.x;
    const int lane = threadIdx.x;
    const int n    = b * 64 + lane;

    float mem = 0.f;
    for (int tb = 0; tb < T_STEPS; tb += 10) {
        float c[10];
#pragma unroll
        for (int i = 0; i < 10; i++) c[i] = cur1[(size_t)(tb + i) * HTOT + n];
#pragma unroll
        for (int i = 0; i < 10; i++) {
            float reset = (mem > THRESH) ? THRESH : 0.f;
            mem = BETA * mem + c[i] - reset;
            unsigned long long m = __ballot(mem > THRESH);
            if (lane == 0) bitsws[(size_t)(tb + i) * 8 + b] = m;
        }
    }
    if (b == 0 && lane == 0) { wsa[0] = 0.f; wsa[1] = 0.f; }
}

// GEMM2 + LIF2: block per output neuron j (0..19 actor, 20 critic).
__global__ __launch_bounds__(128) void k_gemm2(
    const unsigned long long* __restrict__ bitsws,
    const float* __restrict__ aW2, const float* __restrict__ ab2,
    const float* __restrict__ cW2, const float* __restrict__ cb2,
    float* __restrict__ wsa, float* __restrict__ out)
{
    const int j   = blockIdx.x;
    const int tid = threadIdx.x;

    __shared__ float W[256];
    __shared__ float c2[T_STEPS];

    const float* Wsrc = (j < 20) ? (aW2 + j * 256) : cW2;
    for (int i = tid; i < 256; i += 128) W[i] = Wsrc[i];
    const float bias  = (j < 20) ? ab2[j] : cb2[0];
    const int   wbase = (j < 20) ? 0 : 4;
    __syncthreads();

    const int t = tid;
    if (t < T_STEPS) {
        unsigned long long m0 = bitsws[(size_t)t * 8 + wbase + 0];
        unsigned long long m1 = bitsws[(size_t)t * 8 + wbase + 1];
        unsigned long long m2 = bitsws[(size_t)t * 8 + wbase + 2];
        unsigned long long m3 = bitsws[(size_t)t * 8 + wbase + 3];
        float acc = bias;
#pragma unroll
        for (int bitp = 0; bitp < 64; bitp++) {
            acc += ((m0 >> bitp) & 1ULL) ? W[bitp]       : 0.f;
            acc += ((m1 >> bitp) & 1ULL) ? W[64 + bitp]  : 0.f;
            acc += ((m2 >> bitp) & 1ULL) ? W[128 + bitp] : 0.f;
            acc += ((m3 >> bitp) & 1ULL) ? W[192 + bitp] : 0.f;
        }
        c2[t] = acc;
    }
    __syncthreads();

    if (tid == 0) {
        float mem = 0.f, spk = 0.f;
        for (int tt = 0; tt < T_STEPS; tt++) {
            float reset = (mem > THRESH) ? THRESH : 0.f;
            mem = BETA * mem + c2[tt] - reset;
            spk += (mem > THRESH) ? 1.f : 0.f;
        }
        if (j < 10)       atomicAdd(&wsa[0], spk);   // exact: integer-valued floats
        else if (j < 20)  atomicAdd(&wsa[1], spk);
        else              out[2] = mem;
    }
}

__global__ __launch_bounds__(64) void k_final(
    const float* __restrict__ wsa, float* __restrict__ out)
{
    if (threadIdx.x == 0) {
        float a0 = wsa[0], a1 = wsa[1];
        float mx = fmaxf(a0, a1);
        float e0 = expf(a0 - mx), e1 = expf(a1 - mx);
        float inv = 1.f / (e0 + e1);
        out[0] = e0 * inv;
        out[1] = e1 * inv;
    }
}

extern "C" void kernel_launch(void* const* d_in, const int* in_sizes, int n_in,
                              void* d_out, int out_size, void* d_ws, size_t ws_size,
                              hipStream_t stream) {
    const float* x   = (const float*)d_in[0];
    const float* aW1 = (const float*)d_in[1];
    const float* ab1 = (const float*)d_in[2];
    const float* aW2 = (const float*)d_in[3];
    const float* ab2 = (const float*)d_in[4];
    const float* cW1 = (const float*)d_in[5];
    const float* cb1 = (const float*)d_in[6];
    const float* cW2 = (const float*)d_in[7];
    const float* cb2 = (const float*)d_in[8];
    float* out = (float*)d_out;

    const int NS = 128;                                    // fixed (swizzle assumes 128)
    const int nsteps = (D_IN / NS) / 32;                   // 16

    float* P    = (float*)d_ws;                            // [128][100][512]
    float* cur1 = P + (size_t)NS * T_STEPS * HTOT;         // [100][512]
    unsigned long long* bitsws =
        (unsigned long long*)(cur1 + T_STEPS * HTOT);      // [100][8]
    float* wsa = (float*)(bitsws + T_STEPS * 8);           // [2]

    k_gemm1 <<<512, 256, 0, stream>>>(aW1, cW1, x, P, nsteps);
    k_reduce<<<(T_STEPS * HTOT / 4) / 256, 256, 0, stream>>>(P, ab1, cb1, cur1, NS);
    k_lif1  <<<8, 64, 0, stream>>>(cur1, bitsws, wsa);
    k_gemm2 <<<21, 128, 0, stream>>>(bitsws, aW2, ab2, cW2, cb2, wsa, out);
    k_final <<<1, 64, 0, stream>>>(wsa, out);
}